// Round 12
// baseline (457.176 us; speedup 1.0000x reference)
//
#include <hip/hip_runtime.h>

#define T_DIM 512
#define B_DIM 64
#define I_DIM 1024
#define H_DIM 1024
#define G3    3072                 // 3*H
#define M_DIM (T_DIM * B_DIM)      // 32768
#define K_DIM 1024
#define KT    16                   // K_DIM / 64

typedef unsigned short u16;
typedef __bf16 bf16x8 __attribute__((ext_vector_type(8)));
typedef float  f32x4  __attribute__((ext_vector_type(4)));
typedef unsigned short u16x8 __attribute__((ext_vector_type(8)));

__device__ __forceinline__ u16 f2bf(float x) {
  union { float f; unsigned u; } v; v.f = x;
  unsigned r = v.u + 0x7fffu + ((v.u >> 16) & 1u);   // RNE
  return (u16)(r >> 16);
}
__device__ __forceinline__ float bf2f(u16 x) {
  union { unsigned u; float f; } v; v.u = ((unsigned)x) << 16;
  return v.f;
}

// ---------- compaction metadata ----------
// meta[0..512] = offset[t]; meta[513]=M_c; meta[514]=M_pad
__global__ void build_offsets_kernel(const int* __restrict__ L, int* __restrict__ meta) {
  __shared__ int cnt[T_DIM];
  __shared__ int Ls[B_DIM];
  const int t = threadIdx.x;                 // 512 threads
  if (t < B_DIM) Ls[t] = L[t];
  __syncthreads();
  int n = 0;
  #pragma unroll 8
  for (int b = 0; b < B_DIM; ++b) n += (Ls[b] > t) ? 1 : 0;
  cnt[t] = n;
  __syncthreads();
  if (t == 0) {
    int acc = 0;
    for (int s = 0; s < T_DIM; ++s) { int c = cnt[s]; cnt[s] = acc; acc += c; }
    meta[T_DIM] = acc;
    meta[513] = acc;
    meta[514] = (acc + 511) & ~511;          // M_pad (512-mult -> active blocks %8==0)
  }
  __syncthreads();
  meta[t] = cnt[t];
}

// crow[t*64+b] (cast_gather) and crowT[b*512+t] (scans)
__global__ void build_crow_kernel(const int* __restrict__ L, const int* __restrict__ meta,
                                  int* __restrict__ crow, int* __restrict__ crowT) {
  const int t = blockIdx.x;                  // 512 blocks x 64 threads (1 wave)
  const int b = threadIdx.x;
  const bool valid = t < L[b];
  unsigned long long mask = __ballot(valid);
  const int rank = __popcll(mask & ((1ull << b) - 1ull));
  if (valid) {
    const int cr = meta[t] + rank;
    crow[(t << 6) + b] = cr;
    crowT[(b << 9) + t] = cr;
  }
}

// ---------- cast+gather x: f32 full layout -> bf16 compact rows ----------
__global__ void cast_gather_kernel(const float* __restrict__ in, const int* __restrict__ L,
                                   const int* __restrict__ crow, u16* __restrict__ out, int n8) {
  int idx = blockIdx.x * blockDim.x + threadIdx.x;
  int stride = gridDim.x * blockDim.x;
  for (int i = idx; i < n8; i += stride) {
    const int row = i >> 7;                  // source row (t*64+b), 128 chunks of 8
    const int ch  = i & 127;
    const int b = row & 63, t = row >> 6;
    if (t >= L[b]) continue;
    const int cr = crow[row];
    const float4* p = (const float4*)(in + (size_t)row * 1024 + ch * 8);
    float4 a = p[0], bb = p[1];
    u16x8 o;
    o[0] = f2bf(a.x);  o[1] = f2bf(a.y);  o[2] = f2bf(a.z);  o[3] = f2bf(a.w);
    o[4] = f2bf(bb.x); o[5] = f2bf(bb.y); o[6] = f2bf(bb.z); o[7] = f2bf(bb.w);
    *(u16x8*)(out + (size_t)cr * 1024 + ch * 8) = o;
  }
}

// ------- transpose-cast W[1024][3072] f32 -> Wt[3072][1024] bf16 (z picks W1/W2) -------
__global__ void transpose_cast_kernel(const float* __restrict__ W1, const float* __restrict__ W2,
                                      u16* __restrict__ W1t, u16* __restrict__ W2t) {
  __shared__ float tile[32][33];
  const float* W = blockIdx.z ? W2 : W1;
  u16* Wt       = blockIdx.z ? W2t : W1t;
  int n0 = blockIdx.x * 32, k0 = blockIdx.y * 32;
  int tx = threadIdx.x, ty = threadIdx.y;   // blockDim = (32,8)
  #pragma unroll
  for (int dy = 0; dy < 32; dy += 8)
    tile[ty + dy][tx] = W[(size_t)(k0 + ty + dy) * G3 + n0 + tx];
  __syncthreads();
  #pragma unroll
  for (int dy = 0; dy < 32; dy += 8)
    Wt[(size_t)(n0 + ty + dy) * K_DIM + k0 + tx] = f2bf(tile[tx][ty + dy]);
}

// === 256x256 GEMM (R5/R8 schedule: 2 barriers/K-tile, MFMA-shadowed ds_reads) ===
__device__ __forceinline__ void gload_lds16(const void* g, void* l) {
  __builtin_amdgcn_global_load_lds(
      (const __attribute__((address_space(1))) void*)g,
      (__attribute__((address_space(3))) void*)l, 16, 0, 0);
}

__device__ __forceinline__ void stage_half(const u16* __restrict__ G, u16* lbuf,
                                           int rb, int k0, int w, int l) {
  const int cs   = (l & 7) ^ (l >> 3);
  const int rsub = l >> 3;
  #pragma unroll
  for (int r = 0; r < 2; ++r) {
    const int row0 = rb + r * 64 + w * 8;
    gload_lds16(G + (size_t)(row0 + rsub) * K_DIM + k0 + cs * 8,
                lbuf + (size_t)row0 * 64);
  }
}

__device__ __forceinline__ bf16x8 ldfrag(const u16* buf, int row, int ks, int fr, int g4) {
  const int slot = ((ks << 2) + g4) ^ (fr & 7);
  return *(const bf16x8*)(buf + (size_t)row * 64 + slot * 8);
}

__device__ __forceinline__ void read_a(const u16* buf, bf16x8 (&dst)[4][2],
                                       int rbase, int fr, int g4) {
  #pragma unroll
  for (int m = 0; m < 4; ++m) {
    dst[m][0] = ldfrag(buf, rbase + m * 16 + fr, 0, fr, g4);
    dst[m][1] = ldfrag(buf, rbase + m * 16 + fr, 1, fr, g4);
  }
}
__device__ __forceinline__ void read_b(const u16* buf, bf16x8 (&dst)[2][2],
                                       int rbase, int fr, int g4) {
  #pragma unroll
  for (int n = 0; n < 2; ++n) {
    dst[n][0] = ldfrag(buf, rbase + n * 16 + fr, 0, fr, g4);
    dst[n][1] = ldfrag(buf, rbase + n * 16 + fr, 1, fr, g4);
  }
}

#define BARRIER()  do { __builtin_amdgcn_s_barrier(); __builtin_amdgcn_sched_barrier(0); } while (0)
#define LGKM0()    do { asm volatile("s_waitcnt lgkmcnt(0)" ::: "memory"); __builtin_amdgcn_sched_barrier(0); } while (0)

#define MFMA_Q(ACC, AV, BV)                                                            \
  do {                                                                                 \
    __builtin_amdgcn_s_setprio(1);                                                     \
    _Pragma("unroll")                                                                  \
    for (int m = 0; m < 4; ++m)                                                        \
      _Pragma("unroll")                                                                \
      for (int n = 0; n < 2; ++n) {                                                    \
        ACC = __builtin_amdgcn_mfma_f32_16x16x32_bf16(AV[m][0], BV[n][0], ACC, 0, 0, 0); \
        ACC = __builtin_amdgcn_mfma_f32_16x16x32_bf16(AV[m][1], BV[n][1], ACC, 0, 0, 0); \
      }                                                                                \
    __builtin_amdgcn_s_setprio(0);                                                     \
  } while (0)

__global__ __launch_bounds__(512, 2) void gemm256_kernel(
    const u16* __restrict__ A, const u16* __restrict__ Bt,
    const float* __restrict__ bias, u16* __restrict__ C, int N,
    const int* __restrict__ meta) {
  __shared__ u16 As[2][256 * 64];
  __shared__ u16 Bs[2][256 * 64];
  const int tid = threadIdx.x;
  const int l  = tid & 63, w = tid >> 6;
  const int wm = w >> 2,  wn = w & 3;
  const int fr = l & 15,  g4 = l >> 4;

  // active-grid XCD swizzle: only ny = M_pad/256 y-blocks have work
  const int ny   = meta[514] >> 8;
  const int nact = gridDim.x * ny;
  const int q    = nact >> 3;
  const int lin  = blockIdx.y * gridDim.x + blockIdx.x;
  const int idx  = lin >> 3;
  if (idx >= q) return;
  const int swz = (lin & 7) * q + idx;
  const int bx = swz % gridDim.x, by = swz / gridDim.x;
  const int bm = by * 256, bn = bx * 256;

  const u16* Ab = A  + (size_t)bm * K_DIM;
  const u16* Bb = Bt + (size_t)bn * K_DIM;

  // prologue: tile0 fully + tile1 {A-lo, A-hi, B-lo}  (14 loads/thread)
  stage_half(Ab, As[0], 0,   0,  w, l);
  stage_half(Ab, As[0], 128, 0,  w, l);
  stage_half(Bb, Bs[0], 0,   0,  w, l);
  stage_half(Bb, Bs[0], 128, 0,  w, l);
  stage_half(Ab, As[1], 0,   64, w, l);
  stage_half(Ab, As[1], 128, 64, w, l);
  stage_half(Bb, Bs[1], 0,   64, w, l);

  f32x4 acc[8][4] = {};
  bf16x8 av0[4][2], av1[4][2], bv0[2][2], bv1[2][2];

  for (int T = 0; T < KT - 1; ++T) {
    const u16* Ac = As[T & 1];
    const u16* Bc = Bs[T & 1];
    u16* Bn1 = Bs[(T + 1) & 1];
    u16* An2 = As[T & 1];        u16* Bn2 = Bs[T & 1];   // tile T+2 parity == T
    const int k1 = (T + 1) * 64, k2 = (T + 2) * 64;
    const bool st2 = (T + 2) < KT;

    asm volatile("s_waitcnt vmcnt(6)" ::: "memory");
    BARRIER();                     // tile T resident; tile T-1 reads all consumed

    read_a(Ac, av0, wm * 128, fr, g4);
    read_b(Bc, bv0, wn * 64, fr, g4);
    stage_half(Bb, Bn1, 128, k1, w, l);
    LGKM0();

    MFMA_Q(acc[m][n], av0, bv0);
    read_b(Bc, bv1, wn * 64 + 32, fr, g4);
    LGKM0();

    MFMA_Q(acc[m][n + 2], av0, bv1);
    read_a(Ac, av1, wm * 128 + 64, fr, g4);
    LGKM0();
    BARRIER();                     // all waves' tile-T LDS reads complete

    if (st2) {
      stage_half(Ab, An2, 0,   k2, w, l);
      stage_half(Ab, An2, 128, k2, w, l);
      stage_half(Bb, Bn2, 0,   k2, w, l);
    }

    MFMA_Q(acc[m + 4][n + 2], av1, bv1);
    MFMA_Q(acc[m + 4][n],     av1, bv0);
  }

  // ---- peeled final tile ----
  {
    const u16* Ac = As[(KT - 1) & 1];
    const u16* Bc = Bs[(KT - 1) & 1];
    asm volatile("s_waitcnt vmcnt(0)" ::: "memory");
    BARRIER();
    #pragma unroll
    for (int m = 0; m < 4; ++m) {
      av0[m][0] = ldfrag(Ac, wm * 128 + m * 16 + fr, 0, fr, g4);
      av0[m][1] = ldfrag(Ac, wm * 128 + m * 16 + fr, 1, fr, g4);
      av1[m][0] = ldfrag(Ac, wm * 128 + (m + 4) * 16 + fr, 0, fr, g4);
      av1[m][1] = ldfrag(Ac, wm * 128 + (m + 4) * 16 + fr, 1, fr, g4);
    }
    #pragma unroll
    for (int n = 0; n < 2; ++n) {
      bv0[n][0] = ldfrag(Bc, wn * 64 + n * 16 + fr, 0, fr, g4);
      bv0[n][1] = ldfrag(Bc, wn * 64 + n * 16 + fr, 1, fr, g4);
      bv1[n][0] = ldfrag(Bc, wn * 64 + (n + 2) * 16 + fr, 0, fr, g4);
      bv1[n][1] = ldfrag(Bc, wn * 64 + (n + 2) * 16 + fr, 1, fr, g4);
    }
    LGKM0();
    MFMA_Q(acc[m][n],         av0, bv0);
    MFMA_Q(acc[m][n + 2],     av0, bv1);
    MFMA_Q(acc[m + 4][n + 2], av1, bv1);
    MFMA_Q(acc[m + 4][n],     av1, bv0);
    BARRIER();
  }

  // ---- epilogue: per-wave LDS bounce -> fully coalesced 16B stores ----
  float bb[4];
  #pragma unroll
  for (int j = 0; j < 4; ++j) bb[j] = bias[bn + wn * 64 + j * 16 + fr];

  u16* eb = (w < 4) ? ((u16*)As + (size_t)w * 8192)
                    : ((u16*)Bs + (size_t)(w - 4) * 8192);
  #pragma unroll
  for (int i = 0; i < 8; ++i)
    #pragma unroll
    for (int j = 0; j < 4; ++j)
      #pragma unroll
      for (int v = 0; v < 4; ++v) {
        const int row = i * 16 + g4 * 4 + v;
        const int col = j * 16 + fr;
        eb[row * 64 + (col ^ ((row & 12) << 2))] = f2bf(acc[i][j][v] + bb[j]);
      }
  LGKM0();
  #pragma unroll
  for (int c = 0; c < 16; ++c) {
    const int lrow = c * 8 + (l >> 3);
    const int lcol = (l & 7) * 8;
    u16x8 d = *(const u16x8*)&eb[lrow * 64 + (lcol ^ ((lrow & 12) << 2))];
    *(u16x8*)&C[(size_t)(bm + wm * 128 + lrow) * N + (bn + wn * 64 + lcol)] = d;
  }
}

// ---------------- scan step ----------------
__device__ __forceinline__ float stepf(float h, u16 gp, u16 gq, u16 gr) {
  float p = bf2f(gp), q = bf2f(gq), r = bf2f(gr);
  float ii = 1.f / (1.f + __expf(-(p + h)));
  float ff = 1.f / (1.f + __expf(-(q - h)));
  float u  = ii * r + ff * h;
  float e2 = __expf(2.f * u);
  return 1.f - 2.f / (e2 + 1.f);               // tanh(u)
}

#define SD 16     // steps per chunk; ring = 2 x 16 x 3 x 512B = 48KB

// ---- producer-consumer scan: waves 0-3 compute from LDS ring, waves 4-7 stream
//      gates -> LDS via global_load_lds (TLP hides HBM latency, not compiler ILP).
template <int OUT_BF16>
__global__ __launch_bounds__(512) void scan_pc_kernel(
    const u16* __restrict__ gates,   // [M_c][3H] bf16 compact
    const float* __restrict__ h0,    // [B][H]
    const int* __restrict__ L,       // [B]
    const int* __restrict__ crowT,   // [B][T] compact row map
    u16* __restrict__ out_bf,        // [M_c][H] bf16 compact   (layer 1)
    float* __restrict__ out_f,       // [T*B][H] f32 full       (layer 2)
    float* __restrict__ hlast) {     // [B][H]
  __shared__ u16 ring[2][SD * 3 * 256];     // 2 x 24KB
  __shared__ int crs[T_DIM + SD];
  __shared__ float hbuf[256];
  const int b     = blockIdx.x >> 2;
  const int slice = blockIdx.x & 3;
  const int tid   = threadIdx.x;
  const int Lb    = L[b];
  for (int i = tid; i < T_DIM + SD; i += 512)
    crs[i] = (i < Lb) ? crowT[(b << 9) + i] : 0;   // pad: harmless row 0
  __syncthreads();

  const int nch = (Lb + SD - 1) / SD;
  const int jl  = tid & 255;                 // local j
  const int jg  = (slice << 8) + jl;         // global j
  const bool producer = tid >= 256;
  float h = h0[(b << 10) + jg];

  // prologue: producer issues chunk 0
  if (producer && nch > 0) {
    const int pw = (tid - 256) >> 6, half = (tid >> 5) & 1, l32 = tid & 31;
    #pragma unroll
    for (int i = 0; i < 6; ++i) {
      const int q = pw * 12 + i * 2 + half;  // slice 0..47 = (step s, gate g)
      const int s = q / 3, g = q % 3;
      gload_lds16(gates + (size_t)crs[s] * G3 + g * H_DIM + (slice << 8) + l32 * 8,
                  &ring[0][(pw * 12 + i * 2) * 256]);
    }
    asm volatile("s_waitcnt vmcnt(0)" ::: "memory");
  }
  __syncthreads();

  #pragma unroll 1
  for (int c = 0; c < nch; ++c) {
    if (producer) {                          // issue chunk c+1 into other slot
      if (c + 1 < nch) {
        const int pw = (tid - 256) >> 6, half = (tid >> 5) & 1, l32 = tid & 31;
        #pragma unroll
        for (int i = 0; i < 6; ++i) {
          const int q = pw * 12 + i * 2 + half;
          const int s = q / 3, g = q % 3;
          gload_lds16(gates + (size_t)crs[(c + 1) * SD + s] * G3 + g * H_DIM
                            + (slice << 8) + l32 * 8,
                      &ring[(c + 1) & 1][(pw * 12 + i * 2) * 256]);
        }
        asm volatile("s_waitcnt vmcnt(0)" ::: "memory");
      }
    } else {                                 // consume chunk c
      const u16* rb = ring[c & 1];
      const int tbase = c * SD;
      #pragma unroll
      for (int s = 0; s < SD; ++s) {
        if (tbase + s < Lb) {                // wave-uniform guard
          const u16 gp = rb[(s * 3 + 0) * 256 + jl];
          const u16 gq = rb[(s * 3 + 1) * 256 + jl];
          const u16 gr = rb[(s * 3 + 2) * 256 + jl];
          h = stepf(h, gp, gq, gr);
          if (OUT_BF16) out_bf[(size_t)crs[tbase + s] * H_DIM + jg] = f2bf(h);
          else          out_f[((size_t)(tbase + s) * B_DIM + b) * H_DIM + jg] = h;
        }
      }
    }
    __syncthreads();
  }

  if (!producer) {
    hlast[(size_t)b * H_DIM + jg] = h;
    if (!OUT_BF16) hbuf[jl] = h;             // hand off for fused tail
  }
  if (!OUT_BF16) {                           // fused frozen-tail broadcast
    __syncthreads();
    const float hv = hbuf[jl];
    for (int t = Lb + (tid >> 8); t < T_DIM; t += 2)
      out_f[((size_t)t * B_DIM + b) * H_DIM + jg] = hv;
  }
}

extern "C" void kernel_launch(void* const* d_in, const int* in_sizes, int n_in,
                              void* d_out, int out_size, void* d_ws, size_t ws_size,
                              hipStream_t stream) {
  const float* x  = (const float*)d_in[0];
  const float* h0 = (const float*)d_in[1];
  const float* W1 = (const float*)d_in[2];
  const float* b1 = (const float*)d_in[3];
  const float* W2 = (const float*)d_in[4];
  const float* b2 = (const float*)d_in[5];
  const int*   L  = (const int*)d_in[6];

  float* out2 = (float*)d_out;                         // [T][B][H]
  float* hl   = out2 + (size_t)T_DIM * B_DIM * H_DIM;  // h1 [B][H], then h2

  // workspace layout
  char* w = (char*)d_ws;
  u16* xb    = (u16*)(w);                            //  64 MB  x bf16 (compact)
  u16* W1t   = (u16*)(w + (size_t)67108864);         //   6 MB  W1^T bf16
  u16* W2t   = (u16*)(w + (size_t)73400320);         //   6 MB  W2^T bf16
  u16* gates = (u16*)(w + (size_t)79691776);         // 192 MB  gates bf16 (compact, reused)
  u16* out1  = (u16*)(w + (size_t)281018368);        //  64 MB  out1 bf16 (compact)
  int* meta  = (int*)(w + (size_t)348127232);        // offsets + M_c + M_pad
  int* crow  = (int*)(w + (size_t)348131328);        // [T*B] int
  int* crowT = (int*)(w + (size_t)348262400);        // [B*T] int

  build_offsets_kernel<<<1, 512, 0, stream>>>(L, meta);
  build_crow_kernel<<<T_DIM, 64, 0, stream>>>(L, meta, crow, crowT);
  cast_gather_kernel<<<2048, 256, 0, stream>>>(x, L, crow, xb, (T_DIM * B_DIM * I_DIM) / 8);
  transpose_cast_kernel<<<dim3(G3 / 32, K_DIM / 32, 2), dim3(32, 8), 0, stream>>>(
      W1, W2, W1t, W2t);

  // layer 1
  gemm256_kernel<<<dim3(G3 / 256, M_DIM / 256), 512, 0, stream>>>(
      xb, W1t, b1, gates, G3, meta);
  scan_pc_kernel<1><<<B_DIM * 4, 512, 0, stream>>>(
      gates, h0, L, crowT, out1, nullptr, hl);

  // layer 2
  gemm256_kernel<<<dim3(G3 / 256, M_DIM / 256), 512, 0, stream>>>(
      out1, W2t, b2, gates, G3, meta);
  scan_pc_kernel<0><<<B_DIM * 4, 512, 0, stream>>>(
      gates, h0 + B_DIM * H_DIM, L, crowT, nullptr, out2, hl + B_DIM * H_DIM);
}

// Round 13
// 397.015 us; speedup vs baseline: 1.1515x; 1.1515x over previous
//
#include <hip/hip_runtime.h>

#define T_DIM 512
#define B_DIM 64
#define I_DIM 1024
#define H_DIM 1024
#define G3    3072                 // 3*H
#define M_DIM (T_DIM * B_DIM)      // 32768
#define K_DIM 1024
#define KT    16                   // K_DIM / 64

typedef unsigned short u16;
typedef __bf16 bf16x8 __attribute__((ext_vector_type(8)));
typedef float  f32x4  __attribute__((ext_vector_type(4)));
typedef unsigned short u16x8 __attribute__((ext_vector_type(8)));
typedef unsigned short u16x4 __attribute__((ext_vector_type(4)));

__device__ __forceinline__ u16 f2bf(float x) {
  union { float f; unsigned u; } v; v.f = x;
  unsigned r = v.u + 0x7fffu + ((v.u >> 16) & 1u);   // RNE
  return (u16)(r >> 16);
}
__device__ __forceinline__ float bf2f(u16 x) {
  union { unsigned u; float f; } v; v.u = ((unsigned)x) << 16;
  return v.f;
}

// ---------- compaction metadata ----------
// meta[0..512] = offset[t]; meta[513]=M_c; meta[514]=M_pad
__global__ void build_offsets_kernel(const int* __restrict__ L, int* __restrict__ meta) {
  __shared__ int cnt[T_DIM];
  __shared__ int Ls[B_DIM];
  const int t = threadIdx.x;                 // 512 threads
  if (t < B_DIM) Ls[t] = L[t];
  __syncthreads();
  int n = 0;
  #pragma unroll 8
  for (int b = 0; b < B_DIM; ++b) n += (Ls[b] > t) ? 1 : 0;
  cnt[t] = n;
  __syncthreads();
  if (t == 0) {
    int acc = 0;
    for (int s = 0; s < T_DIM; ++s) { int c = cnt[s]; cnt[s] = acc; acc += c; }
    meta[T_DIM] = acc;
    meta[513] = acc;
    meta[514] = (acc + 511) & ~511;          // M_pad (512-mult -> active blocks %8==0)
  }
  __syncthreads();
  meta[t] = cnt[t];
}

// crow[t*64+b] (cast_gather) and crowT[b*512+t] (scans)
__global__ void build_crow_kernel(const int* __restrict__ L, const int* __restrict__ meta,
                                  int* __restrict__ crow, int* __restrict__ crowT) {
  const int t = blockIdx.x;                  // 512 blocks x 64 threads (1 wave)
  const int b = threadIdx.x;
  const bool valid = t < L[b];
  unsigned long long mask = __ballot(valid);
  const int rank = __popcll(mask & ((1ull << b) - 1ull));
  if (valid) {
    const int cr = meta[t] + rank;
    crow[(t << 6) + b] = cr;
    crowT[(b << 9) + t] = cr;
  }
}

// ---------- cast+gather x: f32 full layout -> bf16 compact rows ----------
__global__ void cast_gather_kernel(const float* __restrict__ in, const int* __restrict__ L,
                                   const int* __restrict__ crow, u16* __restrict__ out, int n8) {
  int idx = blockIdx.x * blockDim.x + threadIdx.x;
  int stride = gridDim.x * blockDim.x;
  for (int i = idx; i < n8; i += stride) {
    const int row = i >> 7;                  // source row (t*64+b), 128 chunks of 8
    const int ch  = i & 127;
    const int b = row & 63, t = row >> 6;
    if (t >= L[b]) continue;
    const int cr = crow[row];
    const float4* p = (const float4*)(in + (size_t)row * 1024 + ch * 8);
    float4 a = p[0], bb = p[1];
    u16x8 o;
    o[0] = f2bf(a.x);  o[1] = f2bf(a.y);  o[2] = f2bf(a.z);  o[3] = f2bf(a.w);
    o[4] = f2bf(bb.x); o[5] = f2bf(bb.y); o[6] = f2bf(bb.z); o[7] = f2bf(bb.w);
    *(u16x8*)(out + (size_t)cr * 1024 + ch * 8) = o;
  }
}

// ------- transpose-cast W[1024][3072] f32 -> Wt[3072][1024] bf16 (z picks W1/W2) -------
__global__ void transpose_cast_kernel(const float* __restrict__ W1, const float* __restrict__ W2,
                                      u16* __restrict__ W1t, u16* __restrict__ W2t) {
  __shared__ float tile[32][33];
  const float* W = blockIdx.z ? W2 : W1;
  u16* Wt       = blockIdx.z ? W2t : W1t;
  int n0 = blockIdx.x * 32, k0 = blockIdx.y * 32;
  int tx = threadIdx.x, ty = threadIdx.y;   // blockDim = (32,8)
  #pragma unroll
  for (int dy = 0; dy < 32; dy += 8)
    tile[ty + dy][tx] = W[(size_t)(k0 + ty + dy) * G3 + n0 + tx];
  __syncthreads();
  #pragma unroll
  for (int dy = 0; dy < 32; dy += 8)
    Wt[(size_t)(n0 + ty + dy) * K_DIM + k0 + tx] = f2bf(tile[tx][ty + dy]);
}

// === 256x256 GEMM (R5/R8 schedule: 2 barriers/K-tile, MFMA-shadowed ds_reads) ===
__device__ __forceinline__ void gload_lds16(const void* g, void* l) {
  __builtin_amdgcn_global_load_lds(
      (const __attribute__((address_space(1))) void*)g,
      (__attribute__((address_space(3))) void*)l, 16, 0, 0);
}

__device__ __forceinline__ void stage_half(const u16* __restrict__ G, u16* lbuf,
                                           int rb, int k0, int w, int l) {
  const int cs   = (l & 7) ^ (l >> 3);
  const int rsub = l >> 3;
  #pragma unroll
  for (int r = 0; r < 2; ++r) {
    const int row0 = rb + r * 64 + w * 8;
    gload_lds16(G + (size_t)(row0 + rsub) * K_DIM + k0 + cs * 8,
                lbuf + (size_t)row0 * 64);
  }
}

__device__ __forceinline__ bf16x8 ldfrag(const u16* buf, int row, int ks, int fr, int g4) {
  const int slot = ((ks << 2) + g4) ^ (fr & 7);
  return *(const bf16x8*)(buf + (size_t)row * 64 + slot * 8);
}

__device__ __forceinline__ void read_a(const u16* buf, bf16x8 (&dst)[4][2],
                                       int rbase, int fr, int g4) {
  #pragma unroll
  for (int m = 0; m < 4; ++m) {
    dst[m][0] = ldfrag(buf, rbase + m * 16 + fr, 0, fr, g4);
    dst[m][1] = ldfrag(buf, rbase + m * 16 + fr, 1, fr, g4);
  }
}
__device__ __forceinline__ void read_b(const u16* buf, bf16x8 (&dst)[2][2],
                                       int rbase, int fr, int g4) {
  #pragma unroll
  for (int n = 0; n < 2; ++n) {
    dst[n][0] = ldfrag(buf, rbase + n * 16 + fr, 0, fr, g4);
    dst[n][1] = ldfrag(buf, rbase + n * 16 + fr, 1, fr, g4);
  }
}

#define BARRIER()  do { __builtin_amdgcn_s_barrier(); __builtin_amdgcn_sched_barrier(0); } while (0)
#define LGKM0()    do { asm volatile("s_waitcnt lgkmcnt(0)" ::: "memory"); __builtin_amdgcn_sched_barrier(0); } while (0)

#define MFMA_Q(ACC, AV, BV)                                                            \
  do {                                                                                 \
    __builtin_amdgcn_s_setprio(1);                                                     \
    _Pragma("unroll")                                                                  \
    for (int m = 0; m < 4; ++m)                                                        \
      _Pragma("unroll")                                                                \
      for (int n = 0; n < 2; ++n) {                                                    \
        ACC = __builtin_amdgcn_mfma_f32_16x16x32_bf16(AV[m][0], BV[n][0], ACC, 0, 0, 0); \
        ACC = __builtin_amdgcn_mfma_f32_16x16x32_bf16(AV[m][1], BV[n][1], ACC, 0, 0, 0); \
      }                                                                                \
    __builtin_amdgcn_s_setprio(0);                                                     \
  } while (0)

__global__ __launch_bounds__(512, 2) void gemm256_kernel(
    const u16* __restrict__ A, const u16* __restrict__ Bt,
    const float* __restrict__ bias, u16* __restrict__ C, int N,
    const int* __restrict__ meta) {
  __shared__ u16 As[2][256 * 64];
  __shared__ u16 Bs[2][256 * 64];
  const int tid = threadIdx.x;
  const int l  = tid & 63, w = tid >> 6;
  const int wm = w >> 2,  wn = w & 3;
  const int fr = l & 15,  g4 = l >> 4;

  // active-grid XCD swizzle: only ny = M_pad/256 y-blocks have work
  const int ny   = meta[514] >> 8;
  const int nact = gridDim.x * ny;
  const int q    = nact >> 3;
  const int lin  = blockIdx.y * gridDim.x + blockIdx.x;
  const int idx  = lin >> 3;
  if (idx >= q) return;
  const int swz = (lin & 7) * q + idx;
  const int bx = swz % gridDim.x, by = swz / gridDim.x;
  const int bm = by * 256, bn = bx * 256;

  const u16* Ab = A  + (size_t)bm * K_DIM;
  const u16* Bb = Bt + (size_t)bn * K_DIM;

  // prologue: tile0 fully + tile1 {A-lo, A-hi, B-lo}  (14 loads/thread)
  stage_half(Ab, As[0], 0,   0,  w, l);
  stage_half(Ab, As[0], 128, 0,  w, l);
  stage_half(Bb, Bs[0], 0,   0,  w, l);
  stage_half(Bb, Bs[0], 128, 0,  w, l);
  stage_half(Ab, As[1], 0,   64, w, l);
  stage_half(Ab, As[1], 128, 64, w, l);
  stage_half(Bb, Bs[1], 0,   64, w, l);

  f32x4 acc[8][4] = {};
  bf16x8 av0[4][2], av1[4][2], bv0[2][2], bv1[2][2];

  for (int T = 0; T < KT - 1; ++T) {
    const u16* Ac = As[T & 1];
    const u16* Bc = Bs[T & 1];
    u16* Bn1 = Bs[(T + 1) & 1];
    u16* An2 = As[T & 1];        u16* Bn2 = Bs[T & 1];   // tile T+2 parity == T
    const int k1 = (T + 1) * 64, k2 = (T + 2) * 64;
    const bool st2 = (T + 2) < KT;

    asm volatile("s_waitcnt vmcnt(6)" ::: "memory");
    BARRIER();                     // tile T resident; tile T-1 reads all consumed

    read_a(Ac, av0, wm * 128, fr, g4);
    read_b(Bc, bv0, wn * 64, fr, g4);
    stage_half(Bb, Bn1, 128, k1, w, l);
    LGKM0();

    MFMA_Q(acc[m][n], av0, bv0);
    read_b(Bc, bv1, wn * 64 + 32, fr, g4);
    LGKM0();

    MFMA_Q(acc[m][n + 2], av0, bv1);
    read_a(Ac, av1, wm * 128 + 64, fr, g4);
    LGKM0();
    BARRIER();                     // all waves' tile-T LDS reads complete

    if (st2) {
      stage_half(Ab, An2, 0,   k2, w, l);
      stage_half(Ab, An2, 128, k2, w, l);
      stage_half(Bb, Bn2, 0,   k2, w, l);
    }

    MFMA_Q(acc[m + 4][n + 2], av1, bv1);
    MFMA_Q(acc[m + 4][n],     av1, bv0);
  }

  // ---- peeled final tile ----
  {
    const u16* Ac = As[(KT - 1) & 1];
    const u16* Bc = Bs[(KT - 1) & 1];
    asm volatile("s_waitcnt vmcnt(0)" ::: "memory");
    BARRIER();
    #pragma unroll
    for (int m = 0; m < 4; ++m) {
      av0[m][0] = ldfrag(Ac, wm * 128 + m * 16 + fr, 0, fr, g4);
      av0[m][1] = ldfrag(Ac, wm * 128 + m * 16 + fr, 1, fr, g4);
      av1[m][0] = ldfrag(Ac, wm * 128 + (m + 4) * 16 + fr, 0, fr, g4);
      av1[m][1] = ldfrag(Ac, wm * 128 + (m + 4) * 16 + fr, 1, fr, g4);
    }
    #pragma unroll
    for (int n = 0; n < 2; ++n) {
      bv0[n][0] = ldfrag(Bc, wn * 64 + n * 16 + fr, 0, fr, g4);
      bv0[n][1] = ldfrag(Bc, wn * 64 + n * 16 + fr, 1, fr, g4);
      bv1[n][0] = ldfrag(Bc, wn * 64 + (n + 2) * 16 + fr, 0, fr, g4);
      bv1[n][1] = ldfrag(Bc, wn * 64 + (n + 2) * 16 + fr, 1, fr, g4);
    }
    LGKM0();
    MFMA_Q(acc[m][n],         av0, bv0);
    MFMA_Q(acc[m][n + 2],     av0, bv1);
    MFMA_Q(acc[m + 4][n + 2], av1, bv1);
    MFMA_Q(acc[m + 4][n],     av1, bv0);
    BARRIER();
  }

  // ---- epilogue: per-wave LDS bounce -> fully coalesced 16B stores ----
  float bb[4];
  #pragma unroll
  for (int j = 0; j < 4; ++j) bb[j] = bias[bn + wn * 64 + j * 16 + fr];

  u16* eb = (w < 4) ? ((u16*)As + (size_t)w * 8192)
                    : ((u16*)Bs + (size_t)(w - 4) * 8192);
  #pragma unroll
  for (int i = 0; i < 8; ++i)
    #pragma unroll
    for (int j = 0; j < 4; ++j)
      #pragma unroll
      for (int v = 0; v < 4; ++v) {
        const int row = i * 16 + g4 * 4 + v;
        const int col = j * 16 + fr;
        eb[row * 64 + (col ^ ((row & 12) << 2))] = f2bf(acc[i][j][v] + bb[j]);
      }
  LGKM0();
  #pragma unroll
  for (int c = 0; c < 16; ++c) {
    const int lrow = c * 8 + (l >> 3);
    const int lcol = (l & 7) * 8;
    u16x8 d = *(const u16x8*)&eb[lrow * 64 + (lcol ^ ((lrow & 12) << 2))];
    *(u16x8*)&C[(size_t)(bm + wm * 128 + lrow) * N + (bn + wn * 64 + lcol)] = d;
  }
}

// ---------------- scan step ----------------
__device__ __forceinline__ float stepf(float h, u16 gp, u16 gq, u16 gr) {
  float p = bf2f(gp), q = bf2f(gq), r = bf2f(gr);
  float ii = 1.f / (1.f + __expf(-(p + h)));
  float ff = 1.f / (1.f + __expf(-(q - h)));
  float u  = ii * r + ff * h;
  float e2 = __expf(2.f * u);
  return 1.f - 2.f / (e2 + 1.f);               // tanh(u)
}

#define SD 16     // steps per chunk; ring slot = 16 x 256 x 4 u16 = 32KB

// producer: 48 coalesced scalar loads (all in flight) -> 16 conflict-free ds_write_b64
#define PRODUCE(CC)                                                            \
  do {                                                                         \
    u16 vp[SD], vq[SD], vr[SD];                                                \
    const int base_ = (CC) * SD;                                               \
    _Pragma("unroll")                                                          \
    for (int s_ = 0; s_ < SD; ++s_) {                                          \
      const u16* g_ = gates + (size_t)crs[base_ + s_] * G3 + (slice << 8) + p; \
      vp[s_] = g_[0]; vq[s_] = g_[H_DIM]; vr[s_] = g_[2 * H_DIM];              \
    }                                                                          \
    u16* slot_ = ring[(CC) & 1];                                               \
    _Pragma("unroll")                                                          \
    for (int s_ = 0; s_ < SD; ++s_) {                                          \
      u16x4 w4 = {vp[s_], vq[s_], vr[s_], (u16)0};                             \
      *(u16x4*)&slot_[(s_ * 256 + p) * 4] = w4;                                \
    }                                                                          \
  } while (0)

// consumer: 16 x ds_read_b64 burst, then 16 pure-VALU steps (guards only if PART)
#define CONSUME(CC, PART)                                                      \
  do {                                                                         \
    const u16* slot_ = ring[(CC) & 1];                                         \
    const int base_ = (CC) * SD;                                               \
    u16x4 gg[SD];                                                              \
    _Pragma("unroll")                                                          \
    for (int s_ = 0; s_ < SD; ++s_)                                            \
      gg[s_] = *(const u16x4*)&slot_[(s_ * 256 + jl) * 4];                     \
    _Pragma("unroll")                                                          \
    for (int s_ = 0; s_ < SD; ++s_) {                                          \
      if (!(PART) || base_ + s_ < Lb) {                                        \
        h = stepf(h, gg[s_][0], gg[s_][1], gg[s_][2]);                         \
        if (OUT_BF16) out_bf[(size_t)crs[base_ + s_] * H_DIM + jg] = f2bf(h);  \
        else out_f[((size_t)(base_ + s_) * B_DIM + b) * H_DIM + jg] = h;       \
      }                                                                        \
    }                                                                          \
  } while (0)

template <int OUT_BF16>
__global__ __launch_bounds__(512) void scan_pc_kernel(
    const u16* __restrict__ gates,   // [M_c][3H] bf16 compact
    const float* __restrict__ h0,    // [B][H]
    const int* __restrict__ L,       // [B]
    const int* __restrict__ crowT,   // [B][T] compact row map
    u16* __restrict__ out_bf,        // [M_c][H] bf16 compact   (layer 1)
    float* __restrict__ out_f,       // [T*B][H] f32 full       (layer 2)
    float* __restrict__ hlast) {     // [B][H]
  __shared__ u16 ring[2][SD * 256 * 4];     // 2 x 32KB, [s][jl][pqr_]
  __shared__ int crs[T_DIM + SD];
  __shared__ float hbuf[256];
  const int b     = blockIdx.x >> 2;
  const int slice = blockIdx.x & 3;
  const int tid   = threadIdx.x;
  const int Lb    = L[b];
  for (int i = tid; i < T_DIM + SD; i += 512)
    crs[i] = (i < Lb) ? crowT[(b << 9) + i] : 0;   // pad: harmless row 0
  __syncthreads();

  const int nch   = (Lb + SD - 1) / SD;      // chunks incl. partial
  const int nfull = Lb / SD;                 // full (unconditional) chunks
  const int jl  = tid & 255;                 // consumer j / producer p
  const int p   = jl;
  const int jg  = (slice << 8) + jl;
  const bool producer = tid >= 256;
  float h = h0[(b << 10) + jg];

  if (producer && nch > 0) PRODUCE(0);
  __syncthreads();

  #pragma unroll 1
  for (int c = 0; c < nch; ++c) {
    if (producer) {
      if (c + 1 < nch) PRODUCE(c + 1);
    } else {
      if (c < nfull) CONSUME(c, 0);
      else           CONSUME(c, 1);
    }
    __syncthreads();
  }

  if (!producer) {
    hlast[(size_t)b * H_DIM + jg] = h;
    if (!OUT_BF16) hbuf[jl] = h;             // hand off for fused tail
  }
  if (!OUT_BF16) {                           // fused frozen-tail broadcast
    __syncthreads();
    const float hv = hbuf[jl];
    for (int t = Lb + (tid >> 8); t < T_DIM; t += 2)
      out_f[((size_t)t * B_DIM + b) * H_DIM + jg] = hv;
  }
}

extern "C" void kernel_launch(void* const* d_in, const int* in_sizes, int n_in,
                              void* d_out, int out_size, void* d_ws, size_t ws_size,
                              hipStream_t stream) {
  const float* x  = (const float*)d_in[0];
  const float* h0 = (const float*)d_in[1];
  const float* W1 = (const float*)d_in[2];
  const float* b1 = (const float*)d_in[3];
  const float* W2 = (const float*)d_in[4];
  const float* b2 = (const float*)d_in[5];
  const int*   L  = (const int*)d_in[6];

  float* out2 = (float*)d_out;                         // [T][B][H]
  float* hl   = out2 + (size_t)T_DIM * B_DIM * H_DIM;  // h1 [B][H], then h2

  // workspace layout
  char* w = (char*)d_ws;
  u16* xb    = (u16*)(w);                            //  64 MB  x bf16 (compact)
  u16* W1t   = (u16*)(w + (size_t)67108864);         //   6 MB  W1^T bf16
  u16* W2t   = (u16*)(w + (size_t)73400320);         //   6 MB  W2^T bf16
  u16* gates = (u16*)(w + (size_t)79691776);         // 192 MB  gates bf16 (compact, reused)
  u16* out1  = (u16*)(w + (size_t)281018368);        //  64 MB  out1 bf16 (compact)
  int* meta  = (int*)(w + (size_t)348127232);        // offsets + M_c + M_pad
  int* crow  = (int*)(w + (size_t)348131328);        // [T*B] int
  int* crowT = (int*)(w + (size_t)348262400);        // [B*T] int

  build_offsets_kernel<<<1, 512, 0, stream>>>(L, meta);
  build_crow_kernel<<<T_DIM, 64, 0, stream>>>(L, meta, crow, crowT);
  cast_gather_kernel<<<2048, 256, 0, stream>>>(x, L, crow, xb, (T_DIM * B_DIM * I_DIM) / 8);
  transpose_cast_kernel<<<dim3(G3 / 32, K_DIM / 32, 2), dim3(32, 8), 0, stream>>>(
      W1, W2, W1t, W2t);

  // layer 1
  gemm256_kernel<<<dim3(G3 / 256, M_DIM / 256), 512, 0, stream>>>(
      xb, W1t, b1, gates, G3, meta);
  scan_pc_kernel<1><<<B_DIM * 4, 512, 0, stream>>>(
      gates, h0, L, crowT, out1, nullptr, hl);

  // layer 2
  gemm256_kernel<<<dim3(G3 / 256, M_DIM / 256), 512, 0, stream>>>(
      out1, W2t, b2, gates, G3, meta);
  scan_pc_kernel<0><<<B_DIM * 4, 512, 0, stream>>>(
      gates, h0 + B_DIM * H_DIM, L, crowT, nullptr, out2, hl + B_DIM * H_DIM);
}

// Round 14
// 379.902 us; speedup vs baseline: 1.2034x; 1.0450x over previous
//
#include <hip/hip_runtime.h>

#define T_DIM 512
#define B_DIM 64
#define I_DIM 1024
#define H_DIM 1024
#define G3    3072                 // 3*H
#define M_DIM (T_DIM * B_DIM)      // 32768
#define K_DIM 1024
#define KT    16                   // K_DIM / 64

typedef unsigned short u16;
typedef __bf16 bf16x8 __attribute__((ext_vector_type(8)));
typedef float  f32x4  __attribute__((ext_vector_type(4)));
typedef unsigned short u16x8 __attribute__((ext_vector_type(8)));
typedef unsigned short u16x4 __attribute__((ext_vector_type(4)));

__device__ __forceinline__ u16 f2bf(float x) {
  union { float f; unsigned u; } v; v.f = x;
  unsigned r = v.u + 0x7fffu + ((v.u >> 16) & 1u);   // RNE
  return (u16)(r >> 16);
}
__device__ __forceinline__ float bf2f(u16 x) {
  union { unsigned u; float f; } v; v.u = ((unsigned)x) << 16;
  return v.f;
}

// ---------- merged compaction metadata + row maps (one launch) ----------
// meta[0..512]=offset[t]; meta[513]=M_c; meta[514]=M_pad; crow[t*64+b]; crowT[b*512+t]
__global__ __launch_bounds__(512) void build_all_kernel(
    const int* __restrict__ L, int* __restrict__ meta,
    int* __restrict__ crow, int* __restrict__ crowT) {
  __shared__ int cnt[T_DIM];
  __shared__ int Ls[B_DIM];
  const int t = threadIdx.x;                 // 512 threads
  if (t < B_DIM) Ls[t] = L[t];
  __syncthreads();
  int n = 0;
  #pragma unroll 8
  for (int b = 0; b < B_DIM; ++b) n += (Ls[b] > t) ? 1 : 0;
  cnt[t] = n;
  __syncthreads();
  if (t == 0) {
    int acc = 0;
    for (int s = 0; s < T_DIM; ++s) { int c = cnt[s]; cnt[s] = acc; acc += c; }
    meta[T_DIM] = acc;
    meta[513] = acc;
    meta[514] = (acc + 511) & ~511;          // M_pad (512-mult -> active blocks %8==0)
  }
  __syncthreads();
  meta[t] = cnt[t];
  // row maps: thread t ranks the 64 b's serially (coalesced stores per iteration)
  const int off = cnt[t];
  int rank = 0;
  #pragma unroll 8
  for (int b = 0; b < B_DIM; ++b) {
    if (t < Ls[b]) {
      const int cr = off + rank;
      crow[(t << 6) + b] = cr;
      crowT[(b << 9) + t] = cr;
      ++rank;
    }
  }
}

// ---------- cast+gather x: f32 full layout -> bf16 compact rows ----------
__global__ void cast_gather_kernel(const float* __restrict__ in, const int* __restrict__ L,
                                   const int* __restrict__ crow, u16* __restrict__ out, int n8) {
  int idx = blockIdx.x * blockDim.x + threadIdx.x;
  int stride = gridDim.x * blockDim.x;
  for (int i = idx; i < n8; i += stride) {
    const int row = i >> 7;                  // source row (t*64+b), 128 chunks of 8
    const int ch  = i & 127;
    const int b = row & 63, t = row >> 6;
    if (t >= L[b]) continue;
    const int cr = crow[row];
    const float4* p = (const float4*)(in + (size_t)row * 1024 + ch * 8);
    float4 a = p[0], bb = p[1];
    u16x8 o;
    o[0] = f2bf(a.x);  o[1] = f2bf(a.y);  o[2] = f2bf(a.z);  o[3] = f2bf(a.w);
    o[4] = f2bf(bb.x); o[5] = f2bf(bb.y); o[6] = f2bf(bb.z); o[7] = f2bf(bb.w);
    *(u16x8*)(out + (size_t)cr * 1024 + ch * 8) = o;
  }
}

// ------- transpose-cast W[1024][3072] f32 -> Wt[3072][1024] bf16 (z picks W1/W2) -------
__global__ void transpose_cast_kernel(const float* __restrict__ W1, const float* __restrict__ W2,
                                      u16* __restrict__ W1t, u16* __restrict__ W2t) {
  __shared__ float tile[32][33];
  const float* W = blockIdx.z ? W2 : W1;
  u16* Wt       = blockIdx.z ? W2t : W1t;
  int n0 = blockIdx.x * 32, k0 = blockIdx.y * 32;
  int tx = threadIdx.x, ty = threadIdx.y;   // blockDim = (32,8)
  #pragma unroll
  for (int dy = 0; dy < 32; dy += 8)
    tile[ty + dy][tx] = W[(size_t)(k0 + ty + dy) * G3 + n0 + tx];
  __syncthreads();
  #pragma unroll
  for (int dy = 0; dy < 32; dy += 8)
    Wt[(size_t)(n0 + ty + dy) * K_DIM + k0 + tx] = f2bf(tile[tx][ty + dy]);
}

// === 256x256 GEMM (R5/R8 schedule: 2 barriers/K-tile, MFMA-shadowed ds_reads) ===
__device__ __forceinline__ void gload_lds16(const void* g, void* l) {
  __builtin_amdgcn_global_load_lds(
      (const __attribute__((address_space(1))) void*)g,
      (__attribute__((address_space(3))) void*)l, 16, 0, 0);
}

__device__ __forceinline__ void stage_half(const u16* __restrict__ G, u16* lbuf,
                                           int rb, int k0, int w, int l) {
  const int cs   = (l & 7) ^ (l >> 3);
  const int rsub = l >> 3;
  #pragma unroll
  for (int r = 0; r < 2; ++r) {
    const int row0 = rb + r * 64 + w * 8;
    gload_lds16(G + (size_t)(row0 + rsub) * K_DIM + k0 + cs * 8,
                lbuf + (size_t)row0 * 64);
  }
}

__device__ __forceinline__ bf16x8 ldfrag(const u16* buf, int row, int ks, int fr, int g4) {
  const int slot = ((ks << 2) + g4) ^ (fr & 7);
  return *(const bf16x8*)(buf + (size_t)row * 64 + slot * 8);
}

__device__ __forceinline__ void read_a(const u16* buf, bf16x8 (&dst)[4][2],
                                       int rbase, int fr, int g4) {
  #pragma unroll
  for (int m = 0; m < 4; ++m) {
    dst[m][0] = ldfrag(buf, rbase + m * 16 + fr, 0, fr, g4);
    dst[m][1] = ldfrag(buf, rbase + m * 16 + fr, 1, fr, g4);
  }
}
__device__ __forceinline__ void read_b(const u16* buf, bf16x8 (&dst)[2][2],
                                       int rbase, int fr, int g4) {
  #pragma unroll
  for (int n = 0; n < 2; ++n) {
    dst[n][0] = ldfrag(buf, rbase + n * 16 + fr, 0, fr, g4);
    dst[n][1] = ldfrag(buf, rbase + n * 16 + fr, 1, fr, g4);
  }
}

#define BARRIER()  do { __builtin_amdgcn_s_barrier(); __builtin_amdgcn_sched_barrier(0); } while (0)
#define LGKM0()    do { asm volatile("s_waitcnt lgkmcnt(0)" ::: "memory"); __builtin_amdgcn_sched_barrier(0); } while (0)

#define MFMA_Q(ACC, AV, BV)                                                            \
  do {                                                                                 \
    __builtin_amdgcn_s_setprio(1);                                                     \
    _Pragma("unroll")                                                                  \
    for (int m = 0; m < 4; ++m)                                                        \
      _Pragma("unroll")                                                                \
      for (int n = 0; n < 2; ++n) {                                                    \
        ACC = __builtin_amdgcn_mfma_f32_16x16x32_bf16(AV[m][0], BV[n][0], ACC, 0, 0, 0); \
        ACC = __builtin_amdgcn_mfma_f32_16x16x32_bf16(AV[m][1], BV[n][1], ACC, 0, 0, 0); \
      }                                                                                \
    __builtin_amdgcn_s_setprio(0);                                                     \
  } while (0)

__global__ __launch_bounds__(512, 2) void gemm256_kernel(
    const u16* __restrict__ A, const u16* __restrict__ Bt,
    const float* __restrict__ bias, u16* __restrict__ C, int N,
    const int* __restrict__ meta) {
  __shared__ u16 As[2][256 * 64];
  __shared__ u16 Bs[2][256 * 64];
  const int tid = threadIdx.x;
  const int l  = tid & 63, w = tid >> 6;
  const int wm = w >> 2,  wn = w & 3;
  const int fr = l & 15,  g4 = l >> 4;

  // active-grid XCD swizzle: only ny = M_pad/256 y-blocks have work
  const int ny   = meta[514] >> 8;
  const int nact = gridDim.x * ny;
  const int q    = nact >> 3;
  const int lin  = blockIdx.y * gridDim.x + blockIdx.x;
  const int idx  = lin >> 3;
  if (idx >= q) return;
  const int swz = (lin & 7) * q + idx;
  const int bx = swz % gridDim.x, by = swz / gridDim.x;
  const int bm = by * 256, bn = bx * 256;

  const u16* Ab = A  + (size_t)bm * K_DIM;
  const u16* Bb = Bt + (size_t)bn * K_DIM;

  // prologue: tile0 fully + tile1 {A-lo, A-hi, B-lo}  (14 loads/thread)
  stage_half(Ab, As[0], 0,   0,  w, l);
  stage_half(Ab, As[0], 128, 0,  w, l);
  stage_half(Bb, Bs[0], 0,   0,  w, l);
  stage_half(Bb, Bs[0], 128, 0,  w, l);
  stage_half(Ab, As[1], 0,   64, w, l);
  stage_half(Ab, As[1], 128, 64, w, l);
  stage_half(Bb, Bs[1], 0,   64, w, l);

  f32x4 acc[8][4] = {};
  bf16x8 av0[4][2], av1[4][2], bv0[2][2], bv1[2][2];

  for (int T = 0; T < KT - 1; ++T) {
    const u16* Ac = As[T & 1];
    const u16* Bc = Bs[T & 1];
    u16* Bn1 = Bs[(T + 1) & 1];
    u16* An2 = As[T & 1];        u16* Bn2 = Bs[T & 1];   // tile T+2 parity == T
    const int k1 = (T + 1) * 64, k2 = (T + 2) * 64;
    const bool st2 = (T + 2) < KT;

    asm volatile("s_waitcnt vmcnt(6)" ::: "memory");
    BARRIER();                     // tile T resident; tile T-1 reads all consumed

    read_a(Ac, av0, wm * 128, fr, g4);
    read_b(Bc, bv0, wn * 64, fr, g4);
    stage_half(Bb, Bn1, 128, k1, w, l);
    LGKM0();

    MFMA_Q(acc[m][n], av0, bv0);
    read_b(Bc, bv1, wn * 64 + 32, fr, g4);
    LGKM0();

    MFMA_Q(acc[m][n + 2], av0, bv1);
    read_a(Ac, av1, wm * 128 + 64, fr, g4);
    LGKM0();
    BARRIER();                     // all waves' tile-T LDS reads complete

    if (st2) {
      stage_half(Ab, An2, 0,   k2, w, l);
      stage_half(Ab, An2, 128, k2, w, l);
      stage_half(Bb, Bn2, 0,   k2, w, l);
    }

    MFMA_Q(acc[m + 4][n + 2], av1, bv1);
    MFMA_Q(acc[m + 4][n],     av1, bv0);
  }

  // ---- peeled final tile ----
  {
    const u16* Ac = As[(KT - 1) & 1];
    const u16* Bc = Bs[(KT - 1) & 1];
    asm volatile("s_waitcnt vmcnt(0)" ::: "memory");
    BARRIER();
    #pragma unroll
    for (int m = 0; m < 4; ++m) {
      av0[m][0] = ldfrag(Ac, wm * 128 + m * 16 + fr, 0, fr, g4);
      av0[m][1] = ldfrag(Ac, wm * 128 + m * 16 + fr, 1, fr, g4);
      av1[m][0] = ldfrag(Ac, wm * 128 + (m + 4) * 16 + fr, 0, fr, g4);
      av1[m][1] = ldfrag(Ac, wm * 128 + (m + 4) * 16 + fr, 1, fr, g4);
    }
    #pragma unroll
    for (int n = 0; n < 2; ++n) {
      bv0[n][0] = ldfrag(Bc, wn * 64 + n * 16 + fr, 0, fr, g4);
      bv0[n][1] = ldfrag(Bc, wn * 64 + n * 16 + fr, 1, fr, g4);
      bv1[n][0] = ldfrag(Bc, wn * 64 + (n + 2) * 16 + fr, 0, fr, g4);
      bv1[n][1] = ldfrag(Bc, wn * 64 + (n + 2) * 16 + fr, 1, fr, g4);
    }
    LGKM0();
    MFMA_Q(acc[m][n],         av0, bv0);
    MFMA_Q(acc[m][n + 2],     av0, bv1);
    MFMA_Q(acc[m + 4][n + 2], av1, bv1);
    MFMA_Q(acc[m + 4][n],     av1, bv0);
    BARRIER();
  }

  // ---- epilogue: per-wave LDS bounce -> fully coalesced 16B stores ----
  float bb[4];
  #pragma unroll
  for (int j = 0; j < 4; ++j) bb[j] = bias[bn + wn * 64 + j * 16 + fr];

  u16* eb = (w < 4) ? ((u16*)As + (size_t)w * 8192)
                    : ((u16*)Bs + (size_t)(w - 4) * 8192);
  #pragma unroll
  for (int i = 0; i < 8; ++i)
    #pragma unroll
    for (int j = 0; j < 4; ++j)
      #pragma unroll
      for (int v = 0; v < 4; ++v) {
        const int row = i * 16 + g4 * 4 + v;
        const int col = j * 16 + fr;
        eb[row * 64 + (col ^ ((row & 12) << 2))] = f2bf(acc[i][j][v] + bb[j]);
      }
  LGKM0();
  #pragma unroll
  for (int c = 0; c < 16; ++c) {
    const int lrow = c * 8 + (l >> 3);
    const int lcol = (l & 7) * 8;
    u16x8 d = *(const u16x8*)&eb[lrow * 64 + (lcol ^ ((lrow & 12) << 2))];
    *(u16x8*)&C[(size_t)(bm + wm * 128 + lrow) * N + (bn + wn * 64 + lcol)] = d;
  }
}

// ---------------- scan step: hardware rcp + native exp2 (short chain) ----------------
#define LOG2E  1.4426950408889634f
#define LOG2E2 2.8853900817779268f

__device__ __forceinline__ float stepf(float h, u16 gp, u16 gq, u16 gr) {
  float p = bf2f(gp), q = bf2f(gq), r = bf2f(gr);
  float ii = __builtin_amdgcn_rcpf(1.f + exp2f((-(p + h)) * LOG2E));   // sigmoid(p+h)
  float ff = __builtin_amdgcn_rcpf(1.f + exp2f((h - q) * LOG2E));      // sigmoid(q-h)
  float u  = ii * r + ff * h;
  float e2 = exp2f(u * LOG2E2);                                        // exp(2u)
  return 1.f - 2.f * __builtin_amdgcn_rcpf(e2 + 1.f);                  // tanh(u)
}

#define SD 16     // steps per chunk; ring slot = 16 x 256 x 4 u16 = 32KB

// producer: 48 coalesced scalar loads (all in flight) -> 16 conflict-free ds_write_b64
#define PRODUCE(CC)                                                            \
  do {                                                                         \
    u16 vp[SD], vq[SD], vr[SD];                                                \
    const int base_ = (CC) * SD;                                               \
    _Pragma("unroll")                                                          \
    for (int s_ = 0; s_ < SD; ++s_) {                                          \
      const u16* g_ = gates + (size_t)crs[base_ + s_] * G3 + (slice << 8) + p; \
      vp[s_] = g_[0]; vq[s_] = g_[H_DIM]; vr[s_] = g_[2 * H_DIM];              \
    }                                                                          \
    u16* slot_ = ring[(CC) & 1];                                               \
    _Pragma("unroll")                                                          \
    for (int s_ = 0; s_ < SD; ++s_) {                                          \
      u16x4 w4 = {vp[s_], vq[s_], vr[s_], (u16)0};                             \
      *(u16x4*)&slot_[(s_ * 256 + p) * 4] = w4;                                \
    }                                                                          \
  } while (0)

// consumer: 16 x ds_read_b64 burst, then 16 short-chain steps (guards only if PART)
#define CONSUME(CC, PART)                                                      \
  do {                                                                         \
    const u16* slot_ = ring[(CC) & 1];                                         \
    const int base_ = (CC) * SD;                                               \
    u16x4 gg[SD];                                                              \
    int crl[SD];                                                               \
    _Pragma("unroll")                                                          \
    for (int s_ = 0; s_ < SD; ++s_) {                                          \
      gg[s_] = *(const u16x4*)&slot_[(s_ * 256 + jl) * 4];                     \
      crl[s_] = crs[base_ + s_];                                               \
    }                                                                          \
    _Pragma("unroll")                                                          \
    for (int s_ = 0; s_ < SD; ++s_) {                                          \
      if (!(PART) || base_ + s_ < Lb) {                                        \
        h = stepf(h, gg[s_][0], gg[s_][1], gg[s_][2]);                         \
        if (OUT_BF16) out_bf[(size_t)crl[s_] * H_DIM + jg] = f2bf(h);          \
        else out_f[((size_t)(base_ + s_) * B_DIM + b) * H_DIM + jg] = h;       \
      }                                                                        \
    }                                                                          \
  } while (0)

template <int OUT_BF16>
__global__ __launch_bounds__(512) void scan_pc_kernel(
    const u16* __restrict__ gates,   // [M_c][3H] bf16 compact
    const float* __restrict__ h0,    // [B][H]
    const int* __restrict__ L,       // [B]
    const int* __restrict__ crowT,   // [B][T] compact row map
    u16* __restrict__ out_bf,        // [M_c][H] bf16 compact   (layer 1)
    float* __restrict__ out_f,       // [T*B][H] f32 full       (layer 2)
    float* __restrict__ hlast) {     // [B][H]
  __shared__ u16 ring[2][SD * 256 * 4];     // 2 x 32KB, [s][jl][pqr_]
  __shared__ int crs[T_DIM + SD];
  __shared__ float hbuf[256];
  const int b     = blockIdx.x >> 2;
  const int slice = blockIdx.x & 3;
  const int tid   = threadIdx.x;
  const int Lb    = L[b];
  for (int i = tid; i < T_DIM + SD; i += 512)
    crs[i] = (i < Lb) ? crowT[(b << 9) + i] : 0;   // pad: harmless row 0
  __syncthreads();

  const int nch   = (Lb + SD - 1) / SD;      // chunks incl. partial
  const int nfull = Lb / SD;                 // full (unconditional) chunks
  const int jl  = tid & 255;                 // consumer j / producer p
  const int p   = jl;
  const int jg  = (slice << 8) + jl;
  const bool producer = tid >= 256;
  float h = h0[(b << 10) + jg];

  if (producer && nch > 0) PRODUCE(0);
  __syncthreads();

  #pragma unroll 1
  for (int c = 0; c < nch; ++c) {
    if (producer) {
      if (c + 1 < nch) PRODUCE(c + 1);
    } else {
      if (c < nfull) CONSUME(c, 0);
      else           CONSUME(c, 1);
    }
    __syncthreads();
  }

  if (!producer) {
    hlast[(size_t)b * H_DIM + jg] = h;
    if (!OUT_BF16) hbuf[jl] = h;             // hand off for fused tail
  }
  if (!OUT_BF16) {                           // fused frozen-tail broadcast
    __syncthreads();
    const float hv = hbuf[jl];
    for (int t = Lb + (tid >> 8); t < T_DIM; t += 2)
      out_f[((size_t)t * B_DIM + b) * H_DIM + jg] = hv;
  }
}

extern "C" void kernel_launch(void* const* d_in, const int* in_sizes, int n_in,
                              void* d_out, int out_size, void* d_ws, size_t ws_size,
                              hipStream_t stream) {
  const float* x  = (const float*)d_in[0];
  const float* h0 = (const float*)d_in[1];
  const float* W1 = (const float*)d_in[2];
  const float* b1 = (const float*)d_in[3];
  const float* W2 = (const float*)d_in[4];
  const float* b2 = (const float*)d_in[5];
  const int*   L  = (const int*)d_in[6];

  float* out2 = (float*)d_out;                         // [T][B][H]
  float* hl   = out2 + (size_t)T_DIM * B_DIM * H_DIM;  // h1 [B][H], then h2

  // workspace layout
  char* w = (char*)d_ws;
  u16* xb    = (u16*)(w);                            //  64 MB  x bf16 (compact)
  u16* W1t   = (u16*)(w + (size_t)67108864);         //   6 MB  W1^T bf16
  u16* W2t   = (u16*)(w + (size_t)73400320);         //   6 MB  W2^T bf16
  u16* gates = (u16*)(w + (size_t)79691776);         // 192 MB  gates bf16 (compact, reused)
  u16* out1  = (u16*)(w + (size_t)281018368);        //  64 MB  out1 bf16 (compact)
  int* meta  = (int*)(w + (size_t)348127232);        // offsets + M_c + M_pad
  int* crow  = (int*)(w + (size_t)348131328);        // [T*B] int
  int* crowT = (int*)(w + (size_t)348262400);        // [B*T] int

  build_all_kernel<<<1, 512, 0, stream>>>(L, meta, crow, crowT);
  cast_gather_kernel<<<2048, 256, 0, stream>>>(x, L, crow, xb, (T_DIM * B_DIM * I_DIM) / 8);
  transpose_cast_kernel<<<dim3(G3 / 32, K_DIM / 32, 2), dim3(32, 8), 0, stream>>>(
      W1, W2, W1t, W2t);

  // layer 1
  gemm256_kernel<<<dim3(G3 / 256, M_DIM / 256), 512, 0, stream>>>(
      xb, W1t, b1, gates, G3, meta);
  scan_pc_kernel<1><<<B_DIM * 4, 512, 0, stream>>>(
      gates, h0, L, crowT, out1, nullptr, hl);

  // layer 2
  gemm256_kernel<<<dim3(G3 / 256, M_DIM / 256), 512, 0, stream>>>(
      out1, W2t, b2, gates, G3, meta);
  scan_pc_kernel<0><<<B_DIM * 4, 512, 0, stream>>>(
      gates, h0 + B_DIM * H_DIM, L, crowT, nullptr, out2, hl + B_DIM * H_DIM);
}

// Round 15
// 378.471 us; speedup vs baseline: 1.2080x; 1.0038x over previous
//
#include <hip/hip_runtime.h>

#define T_DIM 512
#define B_DIM 64
#define I_DIM 1024
#define H_DIM 1024
#define G3    3072                 // 3*H
#define M_DIM (T_DIM * B_DIM)      // 32768
#define K_DIM 1024
#define KT    16                   // K_DIM / 64

typedef unsigned short u16;
typedef __bf16 bf16x8 __attribute__((ext_vector_type(8)));
typedef float  f32x4  __attribute__((ext_vector_type(4)));
typedef unsigned short u16x8 __attribute__((ext_vector_type(8)));
typedef unsigned short u16x4 __attribute__((ext_vector_type(4)));

__device__ __forceinline__ u16 f2bf(float x) {
  union { float f; unsigned u; } v; v.f = x;
  unsigned r = v.u + 0x7fffu + ((v.u >> 16) & 1u);   // RNE
  return (u16)(r >> 16);
}
__device__ __forceinline__ float bf2f(u16 x) {
  union { unsigned u; float f; } v; v.u = ((unsigned)x) << 16;
  return v.f;
}

// ---------- merged compaction metadata + row maps (one launch) ----------
__global__ __launch_bounds__(512) void build_all_kernel(
    const int* __restrict__ L, int* __restrict__ meta,
    int* __restrict__ crow, int* __restrict__ crowT) {
  __shared__ int cnt[T_DIM];
  __shared__ int Ls[B_DIM];
  const int t = threadIdx.x;                 // 512 threads
  if (t < B_DIM) Ls[t] = L[t];
  __syncthreads();
  int n = 0;
  #pragma unroll 8
  for (int b = 0; b < B_DIM; ++b) n += (Ls[b] > t) ? 1 : 0;
  cnt[t] = n;
  __syncthreads();
  if (t == 0) {
    int acc = 0;
    for (int s = 0; s < T_DIM; ++s) { int c = cnt[s]; cnt[s] = acc; acc += c; }
    meta[T_DIM] = acc;
    meta[513] = acc;
    meta[514] = (acc + 511) & ~511;          // M_pad (512-mult -> active blocks %8==0)
  }
  __syncthreads();
  meta[t] = cnt[t];
  const int off = cnt[t];
  int rank = 0;
  #pragma unroll 8
  for (int b = 0; b < B_DIM; ++b) {
    if (t < Ls[b]) {
      const int cr = off + rank;
      crow[(t << 6) + b] = cr;
      crowT[(b << 9) + t] = cr;
      ++rank;
    }
  }
}

// ---------- cast+gather x: f32 full layout -> bf16 compact rows ----------
__global__ void cast_gather_kernel(const float* __restrict__ in, const int* __restrict__ L,
                                   const int* __restrict__ crow, u16* __restrict__ out, int n8) {
  int idx = blockIdx.x * blockDim.x + threadIdx.x;
  int stride = gridDim.x * blockDim.x;
  for (int i = idx; i < n8; i += stride) {
    const int row = i >> 7;                  // source row (t*64+b), 128 chunks of 8
    const int ch  = i & 127;
    const int b = row & 63, t = row >> 6;
    if (t >= L[b]) continue;
    const int cr = crow[row];
    const float4* p = (const float4*)(in + (size_t)row * 1024 + ch * 8);
    float4 a = p[0], bb = p[1];
    u16x8 o;
    o[0] = f2bf(a.x);  o[1] = f2bf(a.y);  o[2] = f2bf(a.z);  o[3] = f2bf(a.w);
    o[4] = f2bf(bb.x); o[5] = f2bf(bb.y); o[6] = f2bf(bb.z); o[7] = f2bf(bb.w);
    *(u16x8*)(out + (size_t)cr * 1024 + ch * 8) = o;
  }
}

// ------- transpose-cast W[1024][3072] f32 -> Wt[3072][1024] bf16 (z picks W1/W2) -------
__global__ void transpose_cast_kernel(const float* __restrict__ W1, const float* __restrict__ W2,
                                      u16* __restrict__ W1t, u16* __restrict__ W2t) {
  __shared__ float tile[32][33];
  const float* W = blockIdx.z ? W2 : W1;
  u16* Wt       = blockIdx.z ? W2t : W1t;
  int n0 = blockIdx.x * 32, k0 = blockIdx.y * 32;
  int tx = threadIdx.x, ty = threadIdx.y;   // blockDim = (32,8)
  #pragma unroll
  for (int dy = 0; dy < 32; dy += 8)
    tile[ty + dy][tx] = W[(size_t)(k0 + ty + dy) * G3 + n0 + tx];
  __syncthreads();
  #pragma unroll
  for (int dy = 0; dy < 32; dy += 8)
    Wt[(size_t)(n0 + ty + dy) * K_DIM + k0 + tx] = f2bf(tile[tx][ty + dy]);
}

// === 256x256 GEMM: R5 2-barrier schedule, compiler-scheduled reads/MFMA ===
// Only two intra-tile fences remain: (1) vmcnt(6)+barrier at tile top (tile-T
// residency, cross-wave); (2) lgkm0+barrier at mid (av1 reads drained before
// other waves' T+2 stages overwrite those rows). All other read->MFMA ordering
// is register dataflow the compiler schedules with fine-grained lgkmcnt.
__device__ __forceinline__ void gload_lds16(const void* g, void* l) {
  __builtin_amdgcn_global_load_lds(
      (const __attribute__((address_space(1))) void*)g,
      (__attribute__((address_space(3))) void*)l, 16, 0, 0);
}

__device__ __forceinline__ void stage_half(const u16* __restrict__ G, u16* lbuf,
                                           int rb, int k0, int w, int l) {
  const int cs   = (l & 7) ^ (l >> 3);
  const int rsub = l >> 3;
  #pragma unroll
  for (int r = 0; r < 2; ++r) {
    const int row0 = rb + r * 64 + w * 8;
    gload_lds16(G + (size_t)(row0 + rsub) * K_DIM + k0 + cs * 8,
                lbuf + (size_t)row0 * 64);
  }
}

__device__ __forceinline__ bf16x8 ldfrag(const u16* buf, int row, int ks, int fr, int g4) {
  const int slot = ((ks << 2) + g4) ^ (fr & 7);
  return *(const bf16x8*)(buf + (size_t)row * 64 + slot * 8);
}

__device__ __forceinline__ void read_a(const u16* buf, bf16x8 (&dst)[4][2],
                                       int rbase, int fr, int g4) {
  #pragma unroll
  for (int m = 0; m < 4; ++m) {
    dst[m][0] = ldfrag(buf, rbase + m * 16 + fr, 0, fr, g4);
    dst[m][1] = ldfrag(buf, rbase + m * 16 + fr, 1, fr, g4);
  }
}
__device__ __forceinline__ void read_b(const u16* buf, bf16x8 (&dst)[2][2],
                                       int rbase, int fr, int g4) {
  #pragma unroll
  for (int n = 0; n < 2; ++n) {
    dst[n][0] = ldfrag(buf, rbase + n * 16 + fr, 0, fr, g4);
    dst[n][1] = ldfrag(buf, rbase + n * 16 + fr, 1, fr, g4);
  }
}

#define BARRIER()  do { __builtin_amdgcn_s_barrier(); __builtin_amdgcn_sched_barrier(0); } while (0)
#define LGKM0()    do { asm volatile("s_waitcnt lgkmcnt(0)" ::: "memory"); __builtin_amdgcn_sched_barrier(0); } while (0)

#define MFMA_Q(ACC, AV, BV)                                                            \
  do {                                                                                 \
    _Pragma("unroll")                                                                  \
    for (int m = 0; m < 4; ++m)                                                        \
      _Pragma("unroll")                                                                \
      for (int n = 0; n < 2; ++n) {                                                    \
        ACC = __builtin_amdgcn_mfma_f32_16x16x32_bf16(AV[m][0], BV[n][0], ACC, 0, 0, 0); \
        ACC = __builtin_amdgcn_mfma_f32_16x16x32_bf16(AV[m][1], BV[n][1], ACC, 0, 0, 0); \
      }                                                                                \
  } while (0)

__global__ __launch_bounds__(512, 2) void gemm256_kernel(
    const u16* __restrict__ A, const u16* __restrict__ Bt,
    const float* __restrict__ bias, u16* __restrict__ C, int N,
    const int* __restrict__ meta) {
  __shared__ u16 As[2][256 * 64];
  __shared__ u16 Bs[2][256 * 64];
  const int tid = threadIdx.x;
  const int l  = tid & 63, w = tid >> 6;
  const int wm = w >> 2,  wn = w & 3;
  const int fr = l & 15,  g4 = l >> 4;

  // active-grid XCD swizzle: only ny = M_pad/256 y-blocks have work
  const int ny   = meta[514] >> 8;
  const int nact = gridDim.x * ny;
  const int q    = nact >> 3;
  const int lin  = blockIdx.y * gridDim.x + blockIdx.x;
  const int idx  = lin >> 3;
  if (idx >= q) return;
  const int swz = (lin & 7) * q + idx;
  const int bx = swz % gridDim.x, by = swz / gridDim.x;
  const int bm = by * 256, bn = bx * 256;

  const u16* Ab = A  + (size_t)bm * K_DIM;
  const u16* Bb = Bt + (size_t)bn * K_DIM;

  // prologue: tile0 fully + tile1 {A-lo, A-hi, B-lo}  (14 loads/thread)
  stage_half(Ab, As[0], 0,   0,  w, l);
  stage_half(Ab, As[0], 128, 0,  w, l);
  stage_half(Bb, Bs[0], 0,   0,  w, l);
  stage_half(Bb, Bs[0], 128, 0,  w, l);
  stage_half(Ab, As[1], 0,   64, w, l);
  stage_half(Ab, As[1], 128, 64, w, l);
  stage_half(Bb, Bs[1], 0,   64, w, l);

  f32x4 acc[8][4] = {};
  bf16x8 av0[4][2], av1[4][2], bv0[2][2], bv1[2][2];

  for (int T = 0; T < KT - 1; ++T) {
    const u16* Ac = As[T & 1];
    const u16* Bc = Bs[T & 1];
    u16* Bn1 = Bs[(T + 1) & 1];
    u16* An2 = As[T & 1];        u16* Bn2 = Bs[T & 1];   // tile T+2 parity == T
    const int k1 = (T + 1) * 64, k2 = (T + 2) * 64;
    const bool st2 = (T + 2) < KT;

    asm volatile("s_waitcnt vmcnt(6)" ::: "memory");
    BARRIER();                     // tile T resident everywhere (keep sched wall:
                                   // reads must not hoist above cross-wave barrier)

    read_a(Ac, av0, wm * 128, fr, g4);
    read_b(Bc, bv0, wn * 64, fr, g4);
    stage_half(Bb, Bn1, 128, k1, w, l);
    MFMA_Q(acc[m][n], av0, bv0);       // compiler interleaves reads w/ fine lgkmcnt
    read_b(Bc, bv1, wn * 64 + 32, fr, g4);
    MFMA_Q(acc[m][n + 2], av0, bv1);
    read_a(Ac, av1, wm * 128 + 64, fr, g4);
    asm volatile("s_waitcnt lgkmcnt(0)" ::: "memory");   // av1 landed (rows about
    BARRIER();                     // to be overwritten by other waves' T+2 stage)

    if (st2) {
      stage_half(Ab, An2, 0,   k2, w, l);
      stage_half(Ab, An2, 128, k2, w, l);
      stage_half(Bb, Bn2, 0,   k2, w, l);
    }

    MFMA_Q(acc[m + 4][n + 2], av1, bv1);
    MFMA_Q(acc[m + 4][n],     av1, bv0);
  }

  // ---- peeled final tile ----
  {
    const u16* Ac = As[(KT - 1) & 1];
    const u16* Bc = Bs[(KT - 1) & 1];
    asm volatile("s_waitcnt vmcnt(0)" ::: "memory");
    BARRIER();
    #pragma unroll
    for (int m = 0; m < 4; ++m) {
      av0[m][0] = ldfrag(Ac, wm * 128 + m * 16 + fr, 0, fr, g4);
      av0[m][1] = ldfrag(Ac, wm * 128 + m * 16 + fr, 1, fr, g4);
      av1[m][0] = ldfrag(Ac, wm * 128 + (m + 4) * 16 + fr, 0, fr, g4);
      av1[m][1] = ldfrag(Ac, wm * 128 + (m + 4) * 16 + fr, 1, fr, g4);
    }
    #pragma unroll
    for (int n = 0; n < 2; ++n) {
      bv0[n][0] = ldfrag(Bc, wn * 64 + n * 16 + fr, 0, fr, g4);
      bv0[n][1] = ldfrag(Bc, wn * 64 + n * 16 + fr, 1, fr, g4);
      bv1[n][0] = ldfrag(Bc, wn * 64 + (n + 2) * 16 + fr, 0, fr, g4);
      bv1[n][1] = ldfrag(Bc, wn * 64 + (n + 2) * 16 + fr, 1, fr, g4);
    }
    MFMA_Q(acc[m][n],         av0, bv0);
    MFMA_Q(acc[m][n + 2],     av0, bv1);
    MFMA_Q(acc[m + 4][n + 2], av1, bv1);
    MFMA_Q(acc[m + 4][n],     av1, bv0);
    BARRIER();                     // all reads consumed -> LDS reusable as scratch
  }

  // ---- epilogue: per-wave LDS bounce -> fully coalesced 16B stores ----
  float bb[4];
  #pragma unroll
  for (int j = 0; j < 4; ++j) bb[j] = bias[bn + wn * 64 + j * 16 + fr];

  u16* eb = (w < 4) ? ((u16*)As + (size_t)w * 8192)
                    : ((u16*)Bs + (size_t)(w - 4) * 8192);
  #pragma unroll
  for (int i = 0; i < 8; ++i)
    #pragma unroll
    for (int j = 0; j < 4; ++j)
      #pragma unroll
      for (int v = 0; v < 4; ++v) {
        const int row = i * 16 + g4 * 4 + v;
        const int col = j * 16 + fr;
        eb[row * 64 + (col ^ ((row & 12) << 2))] = f2bf(acc[i][j][v] + bb[j]);
      }
  LGKM0();                            // own-wave ds_writes visible (private region)
  #pragma unroll
  for (int c = 0; c < 16; ++c) {
    const int lrow = c * 8 + (l >> 3);
    const int lcol = (l & 7) * 8;
    u16x8 d = *(const u16x8*)&eb[lrow * 64 + (lcol ^ ((lrow & 12) << 2))];
    *(u16x8*)&C[(size_t)(bm + wm * 128 + lrow) * N + (bn + wn * 64 + lcol)] = d;
  }
}

// ---------------- scan step: hardware rcp + native exp2 (short chain) ----------------
#define LOG2E  1.4426950408889634f
#define LOG2E2 2.8853900817779268f

__device__ __forceinline__ float stepf(float h, u16 gp, u16 gq, u16 gr) {
  float p = bf2f(gp), q = bf2f(gq), r = bf2f(gr);
  float ii = __builtin_amdgcn_rcpf(1.f + exp2f((-(p + h)) * LOG2E));   // sigmoid(p+h)
  float ff = __builtin_amdgcn_rcpf(1.f + exp2f((h - q) * LOG2E));      // sigmoid(q-h)
  float u  = ii * r + ff * h;
  float e2 = exp2f(u * LOG2E2);                                        // exp(2u)
  return 1.f - 2.f * __builtin_amdgcn_rcpf(e2 + 1.f);                  // tanh(u)
}

#define SD 16     // steps per chunk; ring slot = 16 x 256 x 4 u16 = 32KB

#define PRODUCE(CC)                                                            \
  do {                                                                         \
    u16 vp[SD], vq[SD], vr[SD];                                                \
    const int base_ = (CC) * SD;                                               \
    _Pragma("unroll")                                                          \
    for (int s_ = 0; s_ < SD; ++s_) {                                          \
      const u16* g_ = gates + (size_t)crs[base_ + s_] * G3 + (slice << 8) + p; \
      vp[s_] = g_[0]; vq[s_] = g_[H_DIM]; vr[s_] = g_[2 * H_DIM];              \
    }                                                                          \
    u16* slot_ = ring[(CC) & 1];                                               \
    _Pragma("unroll")                                                          \
    for (int s_ = 0; s_ < SD; ++s_) {                                          \
      u16x4 w4 = {vp[s_], vq[s_], vr[s_], (u16)0};                             \
      *(u16x4*)&slot_[(s_ * 256 + p) * 4] = w4;                                \
    }                                                                          \
  } while (0)

#define CONSUME(CC, PART)                                                      \
  do {                                                                         \
    const u16* slot_ = ring[(CC) & 1];                                         \
    const int base_ = (CC) * SD;                                               \
    u16x4 gg[SD];                                                              \
    int crl[SD];                                                               \
    _Pragma("unroll")                                                          \
    for (int s_ = 0; s_ < SD; ++s_) {                                          \
      gg[s_] = *(const u16x4*)&slot_[(s_ * 256 + jl) * 4];                     \
      crl[s_] = crs[base_ + s_];                                               \
    }                                                                          \
    _Pragma("unroll")                                                          \
    for (int s_ = 0; s_ < SD; ++s_) {                                          \
      if (!(PART) || base_ + s_ < Lb) {                                        \
        h = stepf(h, gg[s_][0], gg[s_][1], gg[s_][2]);                         \
        if (OUT_BF16) out_bf[(size_t)crl[s_] * H_DIM + jg] = f2bf(h);          \
        else out_f[((size_t)(base_ + s_) * B_DIM + b) * H_DIM + jg] = h;       \
      }                                                                        \
    }                                                                          \
  } while (0)

template <int OUT_BF16>
__global__ __launch_bounds__(512) void scan_pc_kernel(
    const u16* __restrict__ gates,   // [M_c][3H] bf16 compact
    const float* __restrict__ h0,    // [B][H]
    const int* __restrict__ L,       // [B]
    const int* __restrict__ crowT,   // [B][T] compact row map
    u16* __restrict__ out_bf,        // [M_c][H] bf16 compact   (layer 1)
    float* __restrict__ out_f,       // [T*B][H] f32 full       (layer 2)
    float* __restrict__ hlast) {     // [B][H]
  __shared__ u16 ring[2][SD * 256 * 4];     // 2 x 32KB, [s][jl][pqr_]
  __shared__ int crs[T_DIM + SD];
  __shared__ float hbuf[256];
  const int b     = blockIdx.x >> 2;
  const int slice = blockIdx.x & 3;
  const int tid   = threadIdx.x;
  const int Lb    = L[b];
  for (int i = tid; i < T_DIM + SD; i += 512)
    crs[i] = (i < Lb) ? crowT[(b << 9) + i] : 0;   // pad: harmless row 0
  __syncthreads();

  const int nch   = (Lb + SD - 1) / SD;      // chunks incl. partial
  const int nfull = Lb / SD;                 // full (unconditional) chunks
  const int jl  = tid & 255;                 // consumer j / producer p
  const int p   = jl;
  const int jg  = (slice << 8) + jl;
  const bool producer = tid >= 256;
  float h = h0[(b << 10) + jg];

  if (producer && nch > 0) PRODUCE(0);
  __syncthreads();

  #pragma unroll 1
  for (int c = 0; c < nch; ++c) {
    if (producer) {
      if (c + 1 < nch) PRODUCE(c + 1);
    } else {
      if (c < nfull) CONSUME(c, 0);
      else           CONSUME(c, 1);
    }
    __syncthreads();
  }

  if (!producer) {
    hlast[(size_t)b * H_DIM + jg] = h;
    if (!OUT_BF16) hbuf[jl] = h;             // hand off for fused tail
  }
  if (!OUT_BF16) {                           // fused frozen-tail broadcast
    __syncthreads();
    const float hv = hbuf[jl];
    for (int t = Lb + (tid >> 8); t < T_DIM; t += 2)
      out_f[((size_t)t * B_DIM + b) * H_DIM + jg] = hv;
  }
}

extern "C" void kernel_launch(void* const* d_in, const int* in_sizes, int n_in,
                              void* d_out, int out_size, void* d_ws, size_t ws_size,
                              hipStream_t stream) {
  const float* x  = (const float*)d_in[0];
  const float* h0 = (const float*)d_in[1];
  const float* W1 = (const float*)d_in[2];
  const float* b1 = (const float*)d_in[3];
  const float* W2 = (const float*)d_in[4];
  const float* b2 = (const float*)d_in[5];
  const int*   L  = (const int*)d_in[6];

  float* out2 = (float*)d_out;                         // [T][B][H]
  float* hl   = out2 + (size_t)T_DIM * B_DIM * H_DIM;  // h1 [B][H], then h2

  // workspace layout
  char* w = (char*)d_ws;
  u16* xb    = (u16*)(w);                            //  64 MB  x bf16 (compact)
  u16* W1t   = (u16*)(w + (size_t)67108864);         //   6 MB  W1^T bf16
  u16* W2t   = (u16*)(w + (size_t)73400320);         //   6 MB  W2^T bf16
  u16* gates = (u16*)(w + (size_t)79691776);         // 192 MB  gates bf16 (compact, reused)
  u16* out1  = (u16*)(w + (size_t)281018368);        //  64 MB  out1 bf16 (compact)
  int* meta  = (int*)(w + (size_t)348127232);        // offsets + M_c + M_pad
  int* crow  = (int*)(w + (size_t)348131328);        // [T*B] int
  int* crowT = (int*)(w + (size_t)348262400);        // [B*T] int

  build_all_kernel<<<1, 512, 0, stream>>>(L, meta, crow, crowT);
  cast_gather_kernel<<<2048, 256, 0, stream>>>(x, L, crow, xb, (T_DIM * B_DIM * I_DIM) / 8);
  transpose_cast_kernel<<<dim3(G3 / 32, K_DIM / 32, 2), dim3(32, 8), 0, stream>>>(
      W1, W2, W1t, W2t);

  // layer 1
  gemm256_kernel<<<dim3(G3 / 256, M_DIM / 256), 512, 0, stream>>>(
      xb, W1t, b1, gates, G3, meta);
  scan_pc_kernel<1><<<B_DIM * 4, 512, 0, stream>>>(
      gates, h0, L, crowT, out1, nullptr, hl);

  // layer 2
  gemm256_kernel<<<dim3(G3 / 256, M_DIM / 256), 512, 0, stream>>>(
      out1, W2t, b2, gates, G3, meta);
  scan_pc_kernel<0><<<B_DIM * 4, 512, 0, stream>>>(
      gates, h0 + B_DIM * H_DIM, L, crowT, nullptr, out2, hl + B_DIM * H_DIM);
}